// Round 3
// baseline (279.580 us; speedup 1.0000x reference)
//
#include <hip/hip_runtime.h>
#include <math.h>

#define BB 32
#define TT 48
#define NN 360
#define HH 100
#define DD 64
#define NC 2
#define G4 (4*HH)   // 400

__device__ __forceinline__ float sigmoid_fast(float x) {
    return 1.f / (1.f + __expf(-x));
}
__device__ __forceinline__ float tanh_fast(float x) {
    float ax = fabsf(x);
    float e = __expf(-2.f * ax);
    float t = (1.f - e) / (1.f + e);
    return copysignf(t, x);
}
__device__ __forceinline__ float dot4(float4 a, float4 b) {
    return a.x*b.x + a.y*b.y + a.z*b.z + a.w*b.w;
}

// ---------------- K1: GCN row reduction, 2 rows per wave-iteration ----------------
__global__ __launch_bounds__(256) void gcn_kernel(const float* __restrict__ x,
                                                  const float* __restrict__ w,
                                                  const float* __restrict__ bptr,
                                                  float* __restrict__ gout, int npairs) {
    __shared__ __align__(16) float4 w4[90];
    int tid = threadIdx.x;
    if (tid < 90) w4[tid] = ((const float4*)w)[tid];
    __syncthreads();
    float b = bptr[0];
    int lane = tid & 63;
    int wv = tid >> 6;                       // 0..3
    int stride = 4 * gridDim.x;
    for (int pr = blockIdx.x * 4 + wv; pr < npairs; pr += stride) {
        int row0 = 2 * pr;
        const float4* x0 = (const float4*)(x + (size_t)row0 * NN);
        const float4* x1 = (const float4*)(x + (size_t)(row0 + 1) * NN);
        float4 a0 = x0[lane];
        float4 a1 = x1[lane];
        float4 wa = w4[lane];
        float p0 = dot4(a0, wa);
        float p1 = dot4(a1, wa);
        if (lane < 26) {                     // 90 = 64 + 26
            float4 b0 = x0[lane + 64];
            float4 b1 = x1[lane + 64];
            float4 wb = w4[lane + 64];
            p0 += dot4(b0, wb);
            p1 += dot4(b1, wb);
        }
        #pragma unroll
        for (int off = 32; off; off >>= 1) {
            p0 += __shfl_down(p0, off, 64);
            p1 += __shfl_down(p1, off, 64);
        }
        if (lane == 0) {
            gout[row0]     = fmaxf(p0 + b, 0.f);
            gout[row0 + 1] = fmaxf(p1 + b, 0.f);
        }
    }
}

// ---------------- K2a: transpose W_ih [400,360] -> Wt [360,400] ----------------
__global__ void transpose_wih(const float* __restrict__ Wih, float* __restrict__ Wt) {
    int idx = blockIdx.x * blockDim.x + threadIdx.x;
    if (idx < NN * G4) {
        int n = idx / G4, j = idx % G4;
        Wt[idx] = Wih[j * NN + n];
    }
}

// ---------------- K2: xproj[bt,j] = gout[bt,:]·W_ih[j,:] + bias ----------------
#define BT2 4
__global__ __launch_bounds__(512) void xproj_kernel(const float* __restrict__ gout,
                                                    const float* __restrict__ Wt,
                                                    const float* __restrict__ b_ih,
                                                    const float* __restrict__ b_hh,
                                                    float* __restrict__ xproj) {
    __shared__ __align__(16) float gt[BT2 * NN];
    int bt0 = blockIdx.x * BT2;
    int tid = threadIdx.x;
    for (int i = tid; i < BT2 * NN; i += 512) gt[i] = gout[bt0 * NN + i];
    __syncthreads();
    if (tid < G4) {
        float a0 = 0.f, a1 = 0.f, a2 = 0.f, a3 = 0.f;
        for (int n = 0; n < NN; n += 4) {
            float w0 = Wt[(n+0)*G4 + tid];
            float w1 = Wt[(n+1)*G4 + tid];
            float w2 = Wt[(n+2)*G4 + tid];
            float w3 = Wt[(n+3)*G4 + tid];
            float4 g0 = *(const float4*)&gt[0*NN + n];
            float4 g1 = *(const float4*)&gt[1*NN + n];
            float4 g2 = *(const float4*)&gt[2*NN + n];
            float4 g3 = *(const float4*)&gt[3*NN + n];
            a0 += g0.x*w0 + g0.y*w1 + g0.z*w2 + g0.w*w3;
            a1 += g1.x*w0 + g1.y*w1 + g1.z*w2 + g1.w*w3;
            a2 += g2.x*w0 + g2.y*w1 + g2.z*w2 + g2.w*w3;
            a3 += g3.x*w0 + g3.y*w1 + g3.z*w2 + g3.w*w3;
        }
        float bias = b_ih[tid] + b_hh[tid];
        xproj[(size_t)(bt0 + 0) * G4 + tid] = a0 + bias;
        xproj[(size_t)(bt0 + 1) * G4 + tid] = a1 + bias;
        xproj[(size_t)(bt0 + 2) * G4 + tid] = a2 + bias;
        xproj[(size_t)(bt0 + 3) * G4 + tid] = a3 + bias;
    }
}

// ---------------- K3: fused recurrent LSTM + MIL attention + classifier ----------------
// 448 threads (7 waves). h read from LDS in register-batched groups of 8
// float4 (latency-pipelined); next-timestep xproj prefetched.

#define LD8(v, base) \
    float4 v##0 = h4[(base)+0], v##1 = h4[(base)+1], v##2 = h4[(base)+2], v##3 = h4[(base)+3], \
           v##4 = h4[(base)+4], v##5 = h4[(base)+5], v##6 = h4[(base)+6], v##7 = h4[(base)+7];
#define FMA1(v, k) \
    s0 += wr[4*(k)+0]*v.x; s1 += wr[4*(k)+1]*v.y; s2 += wr[4*(k)+2]*v.z; s3 += wr[4*(k)+3]*v.w;
#define FMA8(v, base) \
    FMA1(v##0,(base)+0) FMA1(v##1,(base)+1) FMA1(v##2,(base)+2) FMA1(v##3,(base)+3) \
    FMA1(v##4,(base)+4) FMA1(v##5,(base)+5) FMA1(v##6,(base)+6) FMA1(v##7,(base)+7)

__global__ __launch_bounds__(448) void lstm_attn_kernel(const float* __restrict__ xproj,
                                                        const float* __restrict__ Whh,
                                                        const float* __restrict__ wa1,
                                                        const float* __restrict__ ba1,
                                                        const float* __restrict__ wa2,
                                                        const float* __restrict__ ba2,
                                                        const float* __restrict__ wc,
                                                        const float* __restrict__ bc,
                                                        float* __restrict__ out) {
    __shared__ __align__(16) float ho[TT * HH];    // 19.2 KB
    __shared__ __align__(16) float h_lds[HH];
    __shared__ float gates[G4];
    __shared__ float sc[TT];
    __shared__ float p[TT];
    __shared__ float M[HH];
    int b = blockIdx.x;
    int tid = threadIdx.x;
    float wr[HH];
    if (tid < G4) {
        #pragma unroll
        for (int k = 0; k < HH; k++) wr[k] = Whh[tid * HH + k];
    }
    float c = 0.f;
    if (tid < HH) h_lds[tid] = 0.f;
    float xp = (tid < G4) ? xproj[(size_t)(b * TT) * G4 + tid] : 0.f;
    __syncthreads();
    for (int t = 0; t < TT; t++) {
        float xp_next = (tid < G4 && t + 1 < TT)
                      ? xproj[(size_t)(b * TT + t + 1) * G4 + tid] : 0.f;
        if (tid < G4) {
            const float4* h4 = (const float4*)h_lds;
            float s0 = 0.f, s1 = 0.f, s2 = 0.f, s3 = 0.f;
            LD8(ua, 0)
            LD8(ub, 8)
            FMA8(ua, 0)
            LD8(uc, 16)
            float4 ulast = h4[24];
            FMA8(ub, 8)
            FMA8(uc, 16)
            FMA1(ulast, 24)
            gates[tid] = xp + (s0 + s1) + (s2 + s3);
        }
        __syncthreads();
        if (tid < HH) {
            float ig = sigmoid_fast(gates[tid]);
            float fg = sigmoid_fast(gates[tid + HH]);
            float gg = tanh_fast(gates[tid + 2*HH]);
            float og = sigmoid_fast(gates[tid + 3*HH]);
            c = fg * c + ig * gg;
            float hh = og * tanh_fast(c);
            h_lds[tid] = hh;
            ho[t * HH + tid] = hh;
        }
        xp = xp_next;
        __syncthreads();
    }
    // ---- MIL attention ----
    int wave = tid >> 6, lane = tid & 63;
    for (int t = wave; t < TT; t += 7) {
        float a = 0.f;
        if (lane < DD) {
            float s = ba1[lane];
            #pragma unroll
            for (int h2 = 0; h2 < HH; h2 += 4) {
                float4 h4v = *(const float4*)&ho[t*HH + h2];
                s += wa1[lane*HH + h2+0]*h4v.x + wa1[lane*HH + h2+1]*h4v.y
                   + wa1[lane*HH + h2+2]*h4v.z + wa1[lane*HH + h2+3]*h4v.w;
            }
            a = tanh_fast(s) * wa2[lane];
        }
        #pragma unroll
        for (int off = 32; off; off >>= 1) a += __shfl_down(a, off, 64);
        if (lane == 0) sc[t] = a + ba2[0];
    }
    __syncthreads();
    if (tid < 64) {
        float v = (lane < TT) ? sc[lane] : -1e30f;
        if (lane < TT) out[BB*NC + b*TT + lane] = v;      // Att (pre-softmax logits)
        float m = v;
        #pragma unroll
        for (int off = 32; off; off >>= 1) m = fmaxf(m, __shfl_xor(m, off, 64));
        float e = (lane < TT) ? __expf(v - m) : 0.f;
        float s = e;
        #pragma unroll
        for (int off = 32; off; off >>= 1) s += __shfl_xor(s, off, 64);
        if (lane < TT) p[lane] = e / s;
    }
    __syncthreads();
    if (tid < HH) {
        float m = 0.f;
        #pragma unroll
        for (int t = 0; t < TT; t++) m += p[t] * ho[t*HH + tid];
        M[tid] = m;
    }
    __syncthreads();
    if (tid == 0) {
        float l0 = bc[0], l1 = bc[1];
        for (int h2 = 0; h2 < HH; h2++) { l0 += M[h2]*wc[h2]; l1 += M[h2]*wc[HH + h2]; }
        float mx = fmaxf(l0, l1);
        float e0 = __expf(l0 - mx), e1 = __expf(l1 - mx);
        float s = e0 + e1;
        out[b*NC + 0] = e0 / s;
        out[b*NC + 1] = e1 / s;
    }
}

extern "C" void kernel_launch(void* const* d_in, const int* in_sizes, int n_in,
                              void* d_out, int out_size, void* d_ws, size_t ws_size,
                              hipStream_t stream) {
    const float* x     = (const float*)d_in[0];
    const float* w_gcn = (const float*)d_in[1];
    const float* b_gcn = (const float*)d_in[2];
    const float* W_ih  = (const float*)d_in[3];
    const float* W_hh  = (const float*)d_in[4];
    const float* b_ih  = (const float*)d_in[5];
    const float* b_hh  = (const float*)d_in[6];
    const float* wa1   = (const float*)d_in[7];
    const float* ba1   = (const float*)d_in[8];
    const float* wa2   = (const float*)d_in[9];
    const float* ba2   = (const float*)d_in[10];
    const float* wc    = (const float*)d_in[11];
    const float* bc    = (const float*)d_in[12];
    float* out = (float*)d_out;
    float* ws  = (float*)d_ws;

    float* gout  = ws;                       // 1536*360   = 552960
    float* Wt    = gout + 552960;            // 360*400    = 144000
    float* xproj = Wt + 144000;              // 1536*400   = 614400

    int npairs = BB * TT * NN / 2;           // 276480
    transpose_wih<<<(NN*G4 + 255)/256, 256, 0, stream>>>(W_ih, Wt);
    gcn_kernel<<<2048, 256, 0, stream>>>(x, w_gcn, b_gcn, gout, npairs);
    xproj_kernel<<<(BB*TT)/BT2, 512, 0, stream>>>(gout, Wt, b_ih, b_hh, xproj);
    lstm_attn_kernel<<<BB, 448, 0, stream>>>(xproj, W_hh, wa1, ba1, wa2, ba2, wc, bc, out);
}

// Round 4
// 238.355 us; speedup vs baseline: 1.1730x; 1.1730x over previous
//
#include <hip/hip_runtime.h>
#include <math.h>

#define BB 32
#define TT 48
#define NN 360
#define HH 100
#define DD 64
#define NC 2
#define G4 (4*HH)   // 400

__device__ __forceinline__ float sigmoid_fast(float x) {
    return 1.f / (1.f + __expf(-x));
}
__device__ __forceinline__ float tanh_fast(float x) {
    float ax = fabsf(x);
    float e = __expf(-2.f * ax);
    float t = (1.f - e) / (1.f + e);
    return copysignf(t, x);
}
__device__ __forceinline__ float dot4(float4 a, float4 b) {
    return a.x*b.x + a.y*b.y + a.z*b.z + a.w*b.w;
}
__device__ __forceinline__ float bcast_lane(float v, int l) {
    return __int_as_float(__builtin_amdgcn_readlane(__float_as_int(v), l));
}

// ---------------- K1: GCN row reduction, 4 rows per wave-iteration ----------------
__global__ __launch_bounds__(256) void gcn_kernel(const float* __restrict__ x,
                                                  const float* __restrict__ w,
                                                  const float* __restrict__ bptr,
                                                  float* __restrict__ gout, int nquads) {
    __shared__ __align__(16) float4 w4[90];
    int tid = threadIdx.x;
    if (tid < 90) w4[tid] = ((const float4*)w)[tid];
    __syncthreads();
    float b = bptr[0];
    int lane = tid & 63;
    int wv = tid >> 6;                       // 0..3
    int stride = 4 * gridDim.x;
    for (int q = blockIdx.x * 4 + wv; q < nquads; q += stride) {
        int row0 = 4 * q;
        const float4* x0 = (const float4*)(x + (size_t)(row0 + 0) * NN);
        const float4* x1 = (const float4*)(x + (size_t)(row0 + 1) * NN);
        const float4* x2 = (const float4*)(x + (size_t)(row0 + 2) * NN);
        const float4* x3 = (const float4*)(x + (size_t)(row0 + 3) * NN);
        float4 a0 = x0[lane];
        float4 a1 = x1[lane];
        float4 a2 = x2[lane];
        float4 a3 = x3[lane];
        float4 wa = w4[lane];
        float p0 = dot4(a0, wa);
        float p1 = dot4(a1, wa);
        float p2 = dot4(a2, wa);
        float p3 = dot4(a3, wa);
        if (lane < 26) {                     // 90 = 64 + 26
            float4 b0 = x0[lane + 64];
            float4 b1 = x1[lane + 64];
            float4 b2 = x2[lane + 64];
            float4 b3 = x3[lane + 64];
            float4 wb = w4[lane + 64];
            p0 += dot4(b0, wb);
            p1 += dot4(b1, wb);
            p2 += dot4(b2, wb);
            p3 += dot4(b3, wb);
        }
        #pragma unroll
        for (int off = 32; off; off >>= 1) {
            p0 += __shfl_down(p0, off, 64);
            p1 += __shfl_down(p1, off, 64);
            p2 += __shfl_down(p2, off, 64);
            p3 += __shfl_down(p3, off, 64);
        }
        if (lane == 0) {
            float4 r;
            r.x = fmaxf(p0 + b, 0.f);
            r.y = fmaxf(p1 + b, 0.f);
            r.z = fmaxf(p2 + b, 0.f);
            r.w = fmaxf(p3 + b, 0.f);
            ((float4*)gout)[q] = r;
        }
    }
}

// ---------------- K2a: transpose W_ih [400,360] -> Wt [360,400] ----------------
__global__ void transpose_wih(const float* __restrict__ Wih, float* __restrict__ Wt) {
    int idx = blockIdx.x * blockDim.x + threadIdx.x;
    if (idx < NN * G4) {
        int n = idx / G4, j = idx % G4;
        Wt[idx] = Wih[j * NN + n];
    }
}

// ---------------- K2: xproj[bt,j] = gout[bt,:]·W_ih[j,:] + bias ----------------
#define BT2 4
__global__ __launch_bounds__(512) void xproj_kernel(const float* __restrict__ gout,
                                                    const float* __restrict__ Wt,
                                                    const float* __restrict__ b_ih,
                                                    const float* __restrict__ b_hh,
                                                    float* __restrict__ xproj) {
    __shared__ __align__(16) float gt[BT2 * NN];
    int bt0 = blockIdx.x * BT2;
    int tid = threadIdx.x;
    for (int i = tid; i < BT2 * NN; i += 512) gt[i] = gout[bt0 * NN + i];
    __syncthreads();
    if (tid < G4) {
        float a0 = 0.f, a1 = 0.f, a2 = 0.f, a3 = 0.f;
        for (int n = 0; n < NN; n += 8) {
            float w0 = Wt[(n+0)*G4 + tid];
            float w1 = Wt[(n+1)*G4 + tid];
            float w2 = Wt[(n+2)*G4 + tid];
            float w3 = Wt[(n+3)*G4 + tid];
            float w4_ = Wt[(n+4)*G4 + tid];
            float w5 = Wt[(n+5)*G4 + tid];
            float w6 = Wt[(n+6)*G4 + tid];
            float w7 = Wt[(n+7)*G4 + tid];
            #pragma unroll
            for (int i = 0; i < 1; i++) {}   // (keep structure flat)
            float4 g0a = *(const float4*)&gt[0*NN + n];
            float4 g0b = *(const float4*)&gt[0*NN + n + 4];
            float4 g1a = *(const float4*)&gt[1*NN + n];
            float4 g1b = *(const float4*)&gt[1*NN + n + 4];
            float4 g2a = *(const float4*)&gt[2*NN + n];
            float4 g2b = *(const float4*)&gt[2*NN + n + 4];
            float4 g3a = *(const float4*)&gt[3*NN + n];
            float4 g3b = *(const float4*)&gt[3*NN + n + 4];
            a0 += g0a.x*w0 + g0a.y*w1 + g0a.z*w2 + g0a.w*w3
                + g0b.x*w4_ + g0b.y*w5 + g0b.z*w6 + g0b.w*w7;
            a1 += g1a.x*w0 + g1a.y*w1 + g1a.z*w2 + g1a.w*w3
                + g1b.x*w4_ + g1b.y*w5 + g1b.z*w6 + g1b.w*w7;
            a2 += g2a.x*w0 + g2a.y*w1 + g2a.z*w2 + g2a.w*w3
                + g2b.x*w4_ + g2b.y*w5 + g2b.z*w6 + g2b.w*w7;
            a3 += g3a.x*w0 + g3a.y*w1 + g3a.z*w2 + g3a.w*w3
                + g3b.x*w4_ + g3b.y*w5 + g3b.z*w6 + g3b.w*w7;
        }
        float bias = b_ih[tid] + b_hh[tid];
        xproj[(size_t)(bt0 + 0) * G4 + tid] = a0 + bias;
        xproj[(size_t)(bt0 + 1) * G4 + tid] = a1 + bias;
        xproj[(size_t)(bt0 + 2) * G4 + tid] = a2 + bias;
        xproj[(size_t)(bt0 + 3) * G4 + tid] = a3 + bias;
    }
}

// ---------------- K3: fused LSTM + MIL attention + classifier ----------------
// Gate matvec uses v_readlane SGPR broadcast of h instead of per-thread LDS
// reads: LDS ops/step drop 175 -> 14; the dot product runs on all 4 SIMDs.
__global__ __launch_bounds__(448) void lstm_attn_kernel(const float* __restrict__ xproj,
                                                        const float* __restrict__ Whh,
                                                        const float* __restrict__ wa1,
                                                        const float* __restrict__ ba1,
                                                        const float* __restrict__ wa2,
                                                        const float* __restrict__ ba2,
                                                        const float* __restrict__ wc,
                                                        const float* __restrict__ bc,
                                                        float* __restrict__ out) {
    __shared__ __align__(16) float ho[TT * HH];    // 19.2 KB
    __shared__ __align__(16) float h_lds[128];     // 100 used; 100..127 stay 0
    __shared__ float gates[G4];
    __shared__ float sc[TT];
    __shared__ float p[TT];
    __shared__ float M[HH];
    int b = blockIdx.x;
    int tid = threadIdx.x;
    int lane = tid & 63;
    float wr[HH];
    if (tid < G4) {
        #pragma unroll
        for (int k = 0; k < HH; k++) wr[k] = Whh[tid * HH + k];
    }
    float c = 0.f;
    if (tid < 128) h_lds[tid] = 0.f;
    float xp = (tid < G4) ? xproj[(size_t)(b * TT) * G4 + tid] : 0.f;
    __syncthreads();
    for (int t = 0; t < TT; t++) {
        float xp_next = (tid < G4 && t + 1 < TT)
                      ? xproj[(size_t)(b * TT + t + 1) * G4 + tid] : 0.f;
        float ha = h_lds[lane];
        float hb = h_lds[64 + lane];
        if (tid < G4) {
            float s0 = 0.f, s1 = 0.f, s2 = 0.f, s3 = 0.f;
            #pragma unroll
            for (int k = 0; k < 64; k += 4) {
                s0 += bcast_lane(ha, k+0) * wr[k+0];
                s1 += bcast_lane(ha, k+1) * wr[k+1];
                s2 += bcast_lane(ha, k+2) * wr[k+2];
                s3 += bcast_lane(ha, k+3) * wr[k+3];
            }
            #pragma unroll
            for (int k = 64; k < 100; k += 4) {
                s0 += bcast_lane(hb, k-64) * wr[k+0];
                s1 += bcast_lane(hb, k-63) * wr[k+1];
                s2 += bcast_lane(hb, k-62) * wr[k+2];
                s3 += bcast_lane(hb, k-61) * wr[k+3];
            }
            gates[tid] = xp + (s0 + s1) + (s2 + s3);
        }
        __syncthreads();
        if (tid < HH) {
            float ig = sigmoid_fast(gates[tid]);
            float fg = sigmoid_fast(gates[tid + HH]);
            float gg = tanh_fast(gates[tid + 2*HH]);
            float og = sigmoid_fast(gates[tid + 3*HH]);
            c = fg * c + ig * gg;
            float hh = og * tanh_fast(c);
            h_lds[tid] = hh;
            ho[t * HH + tid] = hh;
        }
        xp = xp_next;
        __syncthreads();
    }
    // ---- MIL attention ----
    int wave = tid >> 6;
    for (int t = wave; t < TT; t += 7) {
        float a = 0.f;
        if (lane < DD) {
            float s = ba1[lane];
            #pragma unroll
            for (int h2 = 0; h2 < HH; h2 += 4) {
                float4 h4v = *(const float4*)&ho[t*HH + h2];
                s += wa1[lane*HH + h2+0]*h4v.x + wa1[lane*HH + h2+1]*h4v.y
                   + wa1[lane*HH + h2+2]*h4v.z + wa1[lane*HH + h2+3]*h4v.w;
            }
            a = tanh_fast(s) * wa2[lane];
        }
        #pragma unroll
        for (int off = 32; off; off >>= 1) a += __shfl_down(a, off, 64);
        if (lane == 0) sc[t] = a + ba2[0];
    }
    __syncthreads();
    if (tid < 64) {
        float v = (lane < TT) ? sc[lane] : -1e30f;
        if (lane < TT) out[BB*NC + b*TT + lane] = v;      // Att (pre-softmax logits)
        float m = v;
        #pragma unroll
        for (int off = 32; off; off >>= 1) m = fmaxf(m, __shfl_xor(m, off, 64));
        float e = (lane < TT) ? __expf(v - m) : 0.f;
        float s = e;
        #pragma unroll
        for (int off = 32; off; off >>= 1) s += __shfl_xor(s, off, 64);
        if (lane < TT) p[lane] = e / s;
    }
    __syncthreads();
    if (tid < HH) {
        float m = 0.f;
        #pragma unroll
        for (int t = 0; t < TT; t++) m += p[t] * ho[t*HH + tid];
        M[tid] = m;
    }
    __syncthreads();
    if (tid == 0) {
        float l0 = bc[0], l1 = bc[1];
        for (int h2 = 0; h2 < HH; h2++) { l0 += M[h2]*wc[h2]; l1 += M[h2]*wc[HH + h2]; }
        float mx = fmaxf(l0, l1);
        float e0 = __expf(l0 - mx), e1 = __expf(l1 - mx);
        float s = e0 + e1;
        out[b*NC + 0] = e0 / s;
        out[b*NC + 1] = e1 / s;
    }
}

extern "C" void kernel_launch(void* const* d_in, const int* in_sizes, int n_in,
                              void* d_out, int out_size, void* d_ws, size_t ws_size,
                              hipStream_t stream) {
    const float* x     = (const float*)d_in[0];
    const float* w_gcn = (const float*)d_in[1];
    const float* b_gcn = (const float*)d_in[2];
    const float* W_ih  = (const float*)d_in[3];
    const float* W_hh  = (const float*)d_in[4];
    const float* b_ih  = (const float*)d_in[5];
    const float* b_hh  = (const float*)d_in[6];
    const float* wa1   = (const float*)d_in[7];
    const float* ba1   = (const float*)d_in[8];
    const float* wa2   = (const float*)d_in[9];
    const float* ba2   = (const float*)d_in[10];
    const float* wc    = (const float*)d_in[11];
    const float* bc    = (const float*)d_in[12];
    float* out = (float*)d_out;
    float* ws  = (float*)d_ws;

    float* gout  = ws;                       // 1536*360   = 552960
    float* Wt    = gout + 552960;            // 360*400    = 144000
    float* xproj = Wt + 144000;              // 1536*400   = 614400

    int nquads = BB * TT * NN / 4;           // 138240
    transpose_wih<<<(NN*G4 + 255)/256, 256, 0, stream>>>(W_ih, Wt);
    gcn_kernel<<<2048, 256, 0, stream>>>(x, w_gcn, b_gcn, gout, nquads);
    xproj_kernel<<<(BB*TT)/BT2, 512, 0, stream>>>(gout, Wt, b_ih, b_hh, xproj);
    lstm_attn_kernel<<<BB, 448, 0, stream>>>(xproj, W_hh, wa1, ba1, wa2, ba2, wc, bc, out);
}